// Round 2
// baseline (56.456 us; speedup 1.0000x reference)
//
#include <hip/hip_runtime.h>
#include <hip/hip_bf16.h>

#define IPS 704          // INPUTS_PER_SQUARE
#define OPS 16           // OUTPUTS_PER_SQUARE
#define NSQ 64           // NUM_SQUARES
#define MAXA 32          // MAX_ACTIVE
#define ROW_OUT 1024     // NSQ * OPS

__global__ __launch_bounds__(256) void ft_slice_kernel(
    const int* __restrict__ fidx,
    const float* __restrict__ fval,
    const float* __restrict__ weight,
    float* __restrict__ out)
{
    const int b = blockIdx.x;
    const int t = threadIdx.x;

    __shared__ float s_acc[ROW_OUT];
    __shared__ int   s_idx[MAXA];
    __shared__ float s_val[MAXA];

    // zero the accumulator: 256 threads x float4 = 1024 floats
    *reinterpret_cast<float4*>(&s_acc[t * 4]) = make_float4(0.f, 0.f, 0.f, 0.f);

    if (t < MAXA) {
        int idx = fidx[b * MAXA + t];
        float v = fval[b * MAXA + t];
        if (idx < 0) { idx = 0; v = 0.0f; }   // empty slot -> zero contribution
        s_idx[t] = idx;
        s_val[t] = v;
    }
    __syncthreads();

    // thread t: feature m = t>>3, output pair j = (t&7)*2
    const int   m   = t >> 3;
    const int   j   = (t & 7) * 2;
    const int   idx = s_idx[m];
    const float v   = s_val[m];
    const int   sq  = idx / IPS;              // magic-mul div by const

    const float2 w = *reinterpret_cast<const float2*>(
        weight + (size_t)idx * OPS + j);

    atomicAdd(&s_acc[sq * OPS + j],     v * w.x);
    atomicAdd(&s_acc[sq * OPS + j + 1], v * w.y);

    __syncthreads();

    // coalesced float4 row store
    *reinterpret_cast<float4*>(out + (size_t)b * ROW_OUT + t * 4) =
        *reinterpret_cast<const float4*>(&s_acc[t * 4]);
}

extern "C" void kernel_launch(void* const* d_in, const int* in_sizes, int n_in,
                              void* d_out, int out_size, void* d_ws, size_t ws_size,
                              hipStream_t stream)
{
    const int*   fidx   = (const int*)d_in[0];    // (16384, 32) int32
    const float* fval   = (const float*)d_in[1];  // (16384, 32) f32
    const float* weight = (const float*)d_in[2];  // (45056, 16) f32
    float*       out    = (float*)d_out;          // (16384, 1024) f32

    const int batch = in_sizes[0] / MAXA;         // 16384

    ft_slice_kernel<<<batch, 256, 0, stream>>>(fidx, fval, weight, out);
}

// Round 3
// 52.572 us; speedup vs baseline: 1.0739x; 1.0739x over previous
//
#include <hip/hip_runtime.h>
#include <hip/hip_bf16.h>

#define IPS 704          // INPUTS_PER_SQUARE
#define OPS 16           // OUTPUTS_PER_SQUARE
#define NSQ 64           // NUM_SQUARES
#define MAXA 32          // MAX_ACTIVE
#define ROW_OUT 1024     // NSQ * OPS
#define SPB 4            // samples per block

__global__ __launch_bounds__(256) void ft_slice_kernel(
    const int* __restrict__ fidx,
    const float* __restrict__ fval,
    const float* __restrict__ weight,
    float* __restrict__ out)
{
    const int b0 = blockIdx.x * SPB;      // first sample of this block
    const int t  = threadIdx.x;

    __shared__ float s_acc[SPB * ROW_OUT];   // 16 KB
    __shared__ int   s_idx[SPB * MAXA];
    __shared__ float s_val[SPB * MAXA];

    // Issue the block's input loads first (one coalesced 512B segment each).
    int   li = 0;
    float lv = 0.0f;
    if (t < SPB * MAXA)            li = fidx[b0 * MAXA + t];
    else if (t < 2 * SPB * MAXA)   lv = fval[b0 * MAXA + (t - SPB * MAXA)];

    // Zero the accumulator while the loads are in flight.
    #pragma unroll
    for (int k = 0; k < SPB; ++k)
        *reinterpret_cast<float4*>(&s_acc[(k * 256 + t) * 4]) =
            make_float4(0.f, 0.f, 0.f, 0.f);

    if (t < SPB * MAXA)            s_idx[t] = li;
    else if (t < 2 * SPB * MAXA)   s_val[t - SPB * MAXA] = lv;
    __syncthreads();

    // Scatter phase: thread t owns (feature m, float2 slot j2) for ALL SPB
    // samples -> SPB independent gathers issued back-to-back (high MLP).
    const int m  = (t >> 3) & (MAXA - 1);
    const int j2 = (t & 7) * 2;

    int   idxs[SPB];
    float vals[SPB];
    int   sq[SPB];
    float2 w[SPB];

    #pragma unroll
    for (int s = 0; s < SPB; ++s) {
        int   idx = s_idx[s * MAXA + m];
        float v   = s_val[s * MAXA + m];
        if (idx < 0) { idx = 0; v = 0.0f; }   // empty slot
        idxs[s] = idx;
        vals[s] = v;
        sq[s]   = idx / IPS;                  // magic-mul div
        w[s] = *reinterpret_cast<const float2*>(
            weight + (size_t)idx * OPS + j2);
    }

    #pragma unroll
    for (int s = 0; s < SPB; ++s) {
        float* dst = &s_acc[s * ROW_OUT + sq[s] * OPS + j2];
        atomicAdd(dst,     vals[s] * w[s].x);
        atomicAdd(dst + 1, vals[s] * w[s].y);
    }
    __syncthreads();

    // Store: SPB rows are contiguous in global -> one 16 KB coalesced block.
    const float4* src = reinterpret_cast<const float4*>(s_acc);
    float4*       dst = reinterpret_cast<float4*>(out + (size_t)b0 * ROW_OUT);
    #pragma unroll
    for (int k = 0; k < SPB; ++k)
        dst[k * 256 + t] = src[k * 256 + t];
}

extern "C" void kernel_launch(void* const* d_in, const int* in_sizes, int n_in,
                              void* d_out, int out_size, void* d_ws, size_t ws_size,
                              hipStream_t stream)
{
    const int*   fidx   = (const int*)d_in[0];    // (16384, 32) int32
    const float* fval   = (const float*)d_in[1];  // (16384, 32) f32
    const float* weight = (const float*)d_in[2];  // (45056, 16) f32
    float*       out    = (float*)d_out;          // (16384, 1024) f32

    const int batch = in_sizes[0] / MAXA;         // 16384
    ft_slice_kernel<<<batch / SPB, 256, 0, stream>>>(fidx, fval, weight, out);
}

// Round 4
// 22.285 us; speedup vs baseline: 2.5333x; 2.3590x over previous
//
#include <hip/hip_runtime.h>
#include <hip/hip_bf16.h>

#define IPS 704          // INPUTS_PER_SQUARE
#define OPS 16           // OUTPUTS_PER_SQUARE
#define NSQ 64           // NUM_SQUARES
#define MAXA 32          // MAX_ACTIVE
#define ROW_OUT 1024     // NSQ * OPS
#define SPB 8            // samples per block

__global__ __launch_bounds__(256) void ft_slice_kernel(
    const int* __restrict__ fidx,
    const float* __restrict__ fval,
    const float* __restrict__ weight,
    float* __restrict__ out)
{
    const int b0 = blockIdx.x * SPB;      // first sample of this block
    const int t  = threadIdx.x;

    __shared__ int      s_idx[SPB][MAXA];
    __shared__ float    s_val[SPB][MAXA];
    __shared__ unsigned s_mask[SPB * NSQ];   // per-(sample,square) feature bitmask

    // Phase 0: issue input loads into registers; zero the masks meanwhile.
    const int li = fidx[b0 * MAXA + t];      // t indexes (sample s=t>>5, feat f=t&31)
    const float lv = fval[b0 * MAXA + t];
    s_mask[t]       = 0u;
    s_mask[t + 256] = 0u;
    __syncthreads();

    // Phase 1: stage idx/val, build per-square feature bitmasks.
    {
        const int s = t >> 5;
        const int f = t & 31;
        int   idx = li;
        float v   = lv;
        if (idx < 0) { idx = 0; v = 0.0f; }  // empty slot -> zero contribution
        s_idx[s][f] = idx;
        s_val[s][f] = v;
        const int sq = idx / IPS;            // magic-mul div by const
        atomicOr(&s_mask[s * NSQ + sq], 1u << f);
    }
    __syncthreads();

    // Phase 2: thread t owns square t>>2, float4 chunk (t&3)*4, for all SPB
    // samples. Average mask popcount = 32/64 = 0.5 -> ~0.5 gathers per loop.
    const int my_sq  = t >> 2;
    const int my_off = (t & 3) * 4;

    unsigned masks[SPB];
    #pragma unroll
    for (int s = 0; s < SPB; ++s)
        masks[s] = s_mask[s * NSQ + my_sq];

    float4 accs[SPB];
    #pragma unroll
    for (int s = 0; s < SPB; ++s) {
        float4 acc = make_float4(0.f, 0.f, 0.f, 0.f);
        unsigned m = masks[s];
        while (m) {
            const int f = __builtin_ctz(m);
            m &= m - 1;
            const float v = s_val[s][f];
            const float4 w = *reinterpret_cast<const float4*>(
                weight + (size_t)s_idx[s][f] * OPS + my_off);
            acc.x += v * w.x;
            acc.y += v * w.y;
            acc.z += v * w.z;
            acc.w += v * w.w;
        }
        accs[s] = acc;
    }

    // Coalesced stores: 8 x 1KB per wave, 32KB contiguous per block.
    #pragma unroll
    for (int s = 0; s < SPB; ++s)
        *reinterpret_cast<float4*>(out + (size_t)(b0 + s) * ROW_OUT + t * 4) = accs[s];
}

extern "C" void kernel_launch(void* const* d_in, const int* in_sizes, int n_in,
                              void* d_out, int out_size, void* d_ws, size_t ws_size,
                              hipStream_t stream)
{
    const int*   fidx   = (const int*)d_in[0];    // (16384, 32) int32
    const float* fval   = (const float*)d_in[1];  // (16384, 32) f32
    const float* weight = (const float*)d_in[2];  // (45056, 16) f32
    float*       out    = (float*)d_out;          // (16384, 1024) f32

    const int batch = in_sizes[0] / MAXA;         // 16384
    ft_slice_kernel<<<batch / SPB, 256, 0, stream>>>(fidx, fval, weight, out);
}

// Round 6
// 19.504 us; speedup vs baseline: 2.8946x; 1.1426x over previous
//
#include <hip/hip_runtime.h>
#include <hip/hip_bf16.h>

#define IPS 704          // INPUTS_PER_SQUARE
#define OPS 16           // OUTPUTS_PER_SQUARE
#define NSQ 64           // NUM_SQUARES
#define MAXA 32          // MAX_ACTIVE
#define ROW_OUT 1024     // NSQ * OPS
#define SPB 8            // samples per block
#define NPAIR (SPB * MAXA)   // 256 (sample,feature) pairs per block

typedef float f32x4 __attribute__((ext_vector_type(4)));

__global__ __launch_bounds__(256) void ft_slice_kernel(
    const int* __restrict__ fidx,
    const float* __restrict__ fval,
    const float* __restrict__ weight,
    float* __restrict__ out)
{
    const int b0 = blockIdx.x * SPB;      // first sample of this block
    const int t  = threadIdx.x;

    __shared__ int      s_idx[NPAIR];          // 1 KB
    __shared__ float    s_val[NPAIR];          // 1 KB
    __shared__ unsigned s_mask[SPB * NSQ];     // 2 KB  per-(sample,square) bitmask
    __shared__ float    s_w[NPAIR * OPS];      // 16 KB weight rows, chunk-XOR-swizzled

    // Phase 0: load this block's (idx,val); zero masks; stage idx/val.
    int   idx = fidx[b0 * MAXA + t];      // t = pair = (sample s=t>>5, feat f=t&31)
    float v   = fval[b0 * MAXA + t];
    if (idx < 0) { idx = 0; v = 0.0f; }   // empty slot -> zero contribution
    s_mask[t]       = 0u;
    s_mask[t + 256] = 0u;
    s_idx[t] = idx;
    s_val[t] = v;
    const int sq = idx / IPS;             // magic-mul div by const
    __syncthreads();

    // Phase 1a: build per-(sample,square) feature bitmasks.
    atomicOr(&s_mask[(t >> 5) * NSQ + sq], 1u << (t & 31));

    // Phase 1b: prefetch ALL 256 weight rows into LDS with max MLP.
    // 4 lanes per row, each loads one float4 chunk; 4 rows per thread.
    const int my_ch = t & 3;
    #pragma unroll
    for (int c = 0; c < 4; ++c) {
        const int pair = (t >> 2) + 64 * c;
        const int ridx = s_idx[pair];                 // broadcast within lane-quad
        const f32x4 w = *reinterpret_cast<const f32x4*>(
            weight + (size_t)ridx * OPS + my_ch * 4);
        // XOR-swizzle chunk position to spread phase-2 banks
        *reinterpret_cast<f32x4*>(
            &s_w[pair * OPS + ((my_ch ^ (pair & 3)) << 2)]) = w;
    }
    __syncthreads();

    // Phase 2: thread t owns square t>>2, float4 chunk t&3, for all SPB
    // samples. LDS-only divergent loop (avg popcount 0.5/square).
    const int my_sq = t >> 2;

    unsigned masks[SPB];
    #pragma unroll
    for (int s = 0; s < SPB; ++s)
        masks[s] = s_mask[s * NSQ + my_sq];

    f32x4 accs[SPB];
    #pragma unroll
    for (int s = 0; s < SPB; ++s) {
        f32x4 acc = (f32x4)(0.0f);
        unsigned m = masks[s];
        while (m) {
            const int f = __builtin_ctz(m);
            m &= m - 1;
            const int pair = s * MAXA + f;
            const float vv = s_val[pair];
            const f32x4 w = *reinterpret_cast<const f32x4*>(
                &s_w[pair * OPS + ((my_ch ^ (pair & 3)) << 2)]);
            acc += vv * w;
        }
        accs[s] = acc;
    }

    // Non-temporal coalesced stores: 64 MB write stream bypasses L2,
    // keeping the 2.88 MB weight table resident.
    #pragma unroll
    for (int s = 0; s < SPB; ++s)
        __builtin_nontemporal_store(
            accs[s],
            reinterpret_cast<f32x4*>(out + (size_t)(b0 + s) * ROW_OUT + t * 4));

}

extern "C" void kernel_launch(void* const* d_in, const int* in_sizes, int n_in,
                              void* d_out, int out_size, void* d_ws, size_t ws_size,
                              hipStream_t stream)
{
    const int*   fidx   = (const int*)d_in[0];    // (16384, 32) int32
    const float* fval   = (const float*)d_in[1];  // (16384, 32) f32
    const float* weight = (const float*)d_in[2];  // (45056, 16) f32
    float*       out    = (float*)d_out;          // (16384, 1024) f32

    const int batch = in_sizes[0] / MAXA;         // 16384
    ft_slice_kernel<<<batch / SPB, 256, 0, stream>>>(fidx, fval, weight, out);
}

// Round 7
// 19.396 us; speedup vs baseline: 2.9107x; 1.0055x over previous
//
#include <hip/hip_runtime.h>
#include <hip/hip_bf16.h>

#define IPS 704          // INPUTS_PER_SQUARE
#define OPS 16           // OUTPUTS_PER_SQUARE
#define NSQ 64           // NUM_SQUARES
#define MAXA 32          // MAX_ACTIVE
#define ROW_OUT 1024     // NSQ * OPS
#define SPB 8            // samples per block
#define NPAIR (SPB * MAXA)   // 256 (sample,feature) pairs per block

typedef float f32x4 __attribute__((ext_vector_type(4)));

__global__ __launch_bounds__(256) void ft_slice_kernel(
    const int* __restrict__ fidx,
    const float* __restrict__ fval,
    const float* __restrict__ weight,
    float* __restrict__ out)
{
    const int b0 = blockIdx.x * SPB;      // first sample of this block
    const int t  = threadIdx.x;

    __shared__ int      s_idx[NPAIR];          // 1 KB
    __shared__ float    s_val[NPAIR];          // 1 KB
    __shared__ unsigned s_mask[SPB * NSQ];     // 2 KB  per-(sample,square) bitmask
    __shared__ float    s_w[NPAIR * OPS];      // 16 KB weight rows, chunk-XOR-swizzled

    // Phase 0: stream this block's (idx,val) with NT loads (read-once data,
    // keep L2 for the weight table); zero masks; stage idx/val.
    int   idx = __builtin_nontemporal_load(fidx + (size_t)b0 * MAXA + t);
    float v   = __builtin_nontemporal_load(fval + (size_t)b0 * MAXA + t);
    if (idx < 0) { idx = 0; v = 0.0f; }   // empty slot -> zero contribution
    s_mask[t]       = 0u;
    s_mask[t + 256] = 0u;
    s_idx[t] = idx;
    s_val[t] = v;
    const int sq = idx / IPS;             // magic-mul div by const
    __syncthreads();

    // Phase 1a: build per-(sample,square) feature bitmasks.
    atomicOr(&s_mask[(t >> 5) * NSQ + sq], 1u << (t & 31));

    // Phase 1b: prefetch ALL 256 weight rows into LDS with max MLP.
    // 4 lanes per row, each loads one float4 chunk; 4 rows per thread.
    const int my_ch = t & 3;
    #pragma unroll
    for (int c = 0; c < 4; ++c) {
        const int pair = (t >> 2) + 64 * c;
        const int ridx = s_idx[pair];                 // broadcast within lane-quad
        const f32x4 w = *reinterpret_cast<const f32x4*>(
            weight + (size_t)ridx * OPS + my_ch * 4);
        // XOR-swizzle chunk position to spread phase-2 banks
        *reinterpret_cast<f32x4*>(
            &s_w[pair * OPS + ((my_ch ^ (pair & 3)) << 2)]) = w;
    }
    __syncthreads();

    // Phase 2: thread t owns square t>>2, float4 chunk t&3, for all SPB
    // samples. LDS-only divergent loop (avg popcount 0.5/square).
    // Store each sample's result immediately (through L2 -> lazy writeback
    // overlaps the next dispatch; full-line coalesced, no RFO).
    const int my_sq = t >> 2;

    unsigned masks[SPB];
    #pragma unroll
    for (int s = 0; s < SPB; ++s)
        masks[s] = s_mask[s * NSQ + my_sq];

    #pragma unroll
    for (int s = 0; s < SPB; ++s) {
        f32x4 acc = (f32x4)(0.0f);
        unsigned m = masks[s];
        while (m) {
            const int f = __builtin_ctz(m);
            m &= m - 1;
            const int pair = s * MAXA + f;
            const float vv = s_val[pair];
            const f32x4 w = *reinterpret_cast<const f32x4*>(
                &s_w[pair * OPS + ((my_ch ^ (pair & 3)) << 2)]);
            acc += vv * w;
        }
        *reinterpret_cast<f32x4*>(out + (size_t)(b0 + s) * ROW_OUT + t * 4) = acc;
    }
}

extern "C" void kernel_launch(void* const* d_in, const int* in_sizes, int n_in,
                              void* d_out, int out_size, void* d_ws, size_t ws_size,
                              hipStream_t stream)
{
    const int*   fidx   = (const int*)d_in[0];    // (16384, 32) int32
    const float* fval   = (const float*)d_in[1];  // (16384, 32) f32
    const float* weight = (const float*)d_in[2];  // (45056, 16) f32
    float*       out    = (float*)d_out;          // (16384, 1024) f32

    const int batch = in_sizes[0] / MAXA;         // 16384
    ft_slice_kernel<<<batch / SPB, 256, 0, stream>>>(fidx, fval, weight, out);
}